// Round 11
// baseline (100.703 us; speedup 1.0000x reference)
//
#include <hip/hip_runtime.h>
#include <hip/hip_bf16.h>
#include <string.h>

#define NL 32
#define HID 64

// Piecewise-linear f32 cell table over z1 in [-16, 16], 1024 cells (1/32).
// ReLU MLP on a scalar is exactly piecewise-linear; lerp + edge extrapolation
// validated rounds 1-9 (absmax 0.031 vs threshold 0.209, flat across widths
// 1/512..1/32). Cell: float4 (shift, scale=exp(ls), dshift, dscale) = 16 B,
// single ds_read_b128 gather, f32 lerp (fp16 lerp = 3x VALU, round-8 lesson).
#define NCELLS 1024
#define NNODES (NCELLS + 1)
#define SCALE  32.0f
#define OFFSET 512.0f
#define TAB_BYTES ((size_t)NL * NCELLS * sizeof(float4))   // 512 KB

#define TPB 512                      // 8 waves per block
#define RPT 4                        // rows per thread -> 1024 blocks = 4/CU
#define ROWS_PER_BLOCK (TPB * RPT)   // 2048
#define CHUNKS (NCELLS / TPB)        // 2 x 16B global_load_lds per thread/layer

#define BNODES 65                    // nodes per build block (64 cells + edge)
#define BCELLS 64

// ------------- build: 4-way j-split per node, fused cell write -------------
// Round-9 build was latency-bound (serial 4288-FMA chain, 2.5 waves/CU).
// Now 4 threads cooperate per node: each computes h1 (64 FMA) and 16 of the
// 64 h2 rows; LDS combine; fused slope/cell write. Chain ~1100 inst, 4x waves.
__global__ __launch_bounds__(320) void build_cells_kernel(
    const float* __restrict__ W1,
    const float* __restrict__ b1,
    const float* __restrict__ W2,
    const float* __restrict__ b2,
    const float* __restrict__ W3,
    const float* __restrict__ b3,
    float4* __restrict__ tab)
{
    const int tid = threadIdx.x;
    const int l = blockIdx.y;
    const int base = blockIdx.x * BCELLS;

    __shared__ float2 part[BNODES][4];
    __shared__ float2 nodes[BNODES];

    const int ni = tid >> 2;          // node within block: 0..64
    const int sp = tid & 3;           // j-split: 0..3

    const float* __restrict__ w1 = W1 + l * HID;
    const float* __restrict__ c1 = b1 + l * HID;
    const float* __restrict__ w2 = W2 + l * HID * HID;
    const float* __restrict__ c2 = b2 + l * HID;
    const float* __restrict__ w3 = W3 + l * 2 * HID;
    const float* __restrict__ c3 = b3 + l * 2;

    if (ni < BNODES) {
        int node = base + ni;
        float a = -16.0f + (float)node * (1.0f / 32.0f);   // exact in fp32

        float h1[HID];
        #pragma unroll
        for (int k = 0; k < HID; ++k) {
            float v = fmaxf(fmaf(a, w1[k], c1[k]), 0.0f);
            asm volatile("" : "+v"(v));   // pin in VGPR; block remat
            h1[k] = v;
        }

        float o0 = 0.0f;
        float o1 = 0.0f;
        const int j0 = sp * (HID / 4);
        #pragma unroll 2
        for (int j = j0; j < j0 + HID / 4; ++j) {
            const float* __restrict__ w2row = w2 + j * HID;
            float acc0 = c2[j];
            float acc1 = 0.0f;
            #pragma unroll
            for (int k = 0; k < HID; k += 2) {
                acc0 = fmaf(h1[k],     w2row[k],     acc0);
                acc1 = fmaf(h1[k + 1], w2row[k + 1], acc1);
            }
            float h = fmaxf(acc0 + acc1, 0.0f);
            o0 = fmaf(h, w3[j], o0);
            o1 = fmaf(h, w3[HID + j], o1);
        }
        part[ni][sp] = make_float2(o0, o1);
    }
    __syncthreads();

    if (tid < BNODES) {
        float2 p0 = part[tid][0];
        float2 p1 = part[tid][1];
        float2 p2 = part[tid][2];
        float2 p3 = part[tid][3];
        float o0 = c3[0] + ((p0.x + p1.x) + (p2.x + p3.x));
        float o1 = c3[1] + ((p0.y + p1.y) + (p2.y + p3.y));
        nodes[tid] = make_float2(o0, expf(o1));   // (shift, scale)
    }
    __syncthreads();

    if (tid < BCELLS) {
        float2 v0 = nodes[tid];
        float2 v1 = nodes[tid + 1];
        tab[(size_t)l * NCELLS + base + tid] =
            make_float4(v0.x, v0.y, v1.x - v0.x, v1.y - v0.y);
    }
}

// ---------------- helpers ---------------------------------------------------
__device__ __forceinline__ float2 nt_load_f2(const float* p) {
    unsigned long long raw =
        __builtin_nontemporal_load((const unsigned long long*)p);
    float2 v;
    memcpy(&v, &raw, 8);
    return v;
}
__device__ __forceinline__ void nt_store_f2(float* p, float2 v) {
    unsigned long long raw;
    memcpy(&raw, &v, 8);
    __builtin_nontemporal_store(raw, (unsigned long long*)p);
}

// async global->LDS DMA, 16 B per lane; LDS dest wave-uniform base,
// lane i lands at base + i*16 (linear lane order -> legal here).
__device__ __forceinline__ void gl2lds16(const float4* g, float4* l) {
    __builtin_amdgcn_global_load_lds(
        (const __attribute__((address_space(1))) void*)g,
        (__attribute__((address_space(3))) void*)l,
        16, 0, 0);
}

// ---------------- main pass: f32 LDS cell table, DMA staging, 4 blocks/CU --
// Round-9 structure, RPT 8->4: grid 1024 = 4 blocks/CU (32 KB LDS each).
// Independent blocks' barrier/drain phases interleave -> higher LDS-pipe
// utilization. launch_bounds(512,8) caps VGPR at 64 so 4 blocks co-reside.
__global__ __launch_bounds__(TPB, 8) void flow_lds_kernel(
    const float* __restrict__ x,
    const float4* __restrict__ tabg,
    float* __restrict__ out,
    int nrows)
{
    __shared__ float4 buf[2][NCELLS];   // 2 x 16 KiB

    const int tid = threadIdx.x;
    const int wbase = tid & ~63;        // wave-uniform lane-0 index
    const size_t rbase = (size_t)blockIdx.x * ROWS_PER_BLOCK;

    float a[RPT], b[RPT];
    #pragma unroll
    for (int i = 0; i < RPT; ++i) {
        size_t r = rbase + (size_t)i * TPB + tid;
        float2 z = (r < (size_t)nrows) ? nt_load_f2(x + 2 * r)
                                       : make_float2(0.f, 0.f);
        a[i] = z.x;
        b[i] = z.y;
    }

    // stage layer 0 into buf[0] (DMA); __syncthreads drains vmcnt
    #pragma unroll
    for (int c = 0; c < CHUNKS; ++c)
        gl2lds16(tabg + c * TPB + tid, &buf[0][c * TPB + wbase]);
    __syncthreads();

    int cur = 0;
    for (int l = 0; l < NL; ++l) {
        // issue next-layer DMA into the other half (in flight during gather)
        if (l + 1 < NL) {
            const float4* __restrict__ src = tabg + (size_t)(l + 1) * NCELLS;
            #pragma unroll
            for (int c = 0; c < CHUNKS; ++c)
                gl2lds16(src + c * TPB + tid, &buf[cur ^ 1][c * TPB + wbase]);
        }

        // gather-compute current layer from buf[cur] (f32 lerp, 3 fmaf)
        #pragma unroll
        for (int i = 0; i < RPT; ++i) {
            float t = fmaf(a[i], SCALE, OFFSET);
            int idx = (int)t;
            idx = idx < 0 ? 0 : (idx > NCELLS - 1 ? NCELLS - 1 : idx);
            float f = t - (float)idx;            // out-of-range -> extrapolate
            float4 nd = buf[cur][idx];
            float sh = fmaf(f, nd.z, nd.x);
            float sc = fmaf(f, nd.w, nd.y);
            float nb = fmaf(b[i], sc, sh);
            b[i] = a[i];
            a[i] = nb;
        }

        __syncthreads();   // waits vmcnt(0) + lgkmcnt(0), then barrier
        cur ^= 1;
    }

    #pragma unroll
    for (int i = 0; i < RPT; ++i) {
        size_t r = rbase + (size_t)i * TPB + tid;
        if (r < (size_t)nrows)
            nt_store_f2(out + 2 * r, make_float2(a[i], b[i]));
    }
}

// ---------------- fallback: direct fp32 (ws too small) ---------------------
__global__ __launch_bounds__(256, 2) void flow_fp32_kernel(
    const float* __restrict__ x,
    const float* __restrict__ W1,
    const float* __restrict__ b1,
    const float* __restrict__ W2,
    const float* __restrict__ b2,
    const float* __restrict__ W3,
    const float* __restrict__ b3,
    float* __restrict__ out,
    int nrows)
{
    int row = blockIdx.x * blockDim.x + threadIdx.x;
    if (row >= nrows) return;

    float2 z = reinterpret_cast<const float2*>(x)[row];
    float a = z.x;
    float b = z.y;

    for (int l = 0; l < NL; ++l) {
        const float* __restrict__ w1 = W1 + l * HID;
        const float* __restrict__ c1 = b1 + l * HID;
        const float* __restrict__ w2 = W2 + l * HID * HID;
        const float* __restrict__ c2 = b2 + l * HID;
        const float* __restrict__ w3 = W3 + l * 2 * HID;
        const float* __restrict__ c3 = b3 + l * 2;

        float h1[HID];
        #pragma unroll
        for (int k = 0; k < HID; ++k) {
            float v = fmaxf(fmaf(a, w1[k], c1[k]), 0.0f);
            asm volatile("" : "+v"(v));
            h1[k] = v;
        }

        float o0 = c3[0];
        float o1 = c3[1];

        #pragma unroll 2
        for (int j = 0; j < HID; ++j) {
            const float* __restrict__ w2row = w2 + j * HID;
            float acc0 = c2[j];
            float acc1 = 0.0f;
            #pragma unroll
            for (int k = 0; k < HID; k += 2) {
                acc0 = fmaf(h1[k],     w2row[k],     acc0);
                acc1 = fmaf(h1[k + 1], w2row[k + 1], acc1);
            }
            float h = fmaxf(acc0 + acc1, 0.0f);
            o0 = fmaf(h, w3[j], o0);
            o1 = fmaf(h, w3[HID + j], o1);
        }

        float nb = fmaf(b, __expf(o1), o0);
        b = a;
        a = nb;
    }

    reinterpret_cast<float2*>(out)[row] = make_float2(a, b);
}

extern "C" void kernel_launch(void* const* d_in, const int* in_sizes, int n_in,
                              void* d_out, int out_size, void* d_ws, size_t ws_size,
                              hipStream_t stream)
{
    const float* x  = (const float*)d_in[0];
    const float* W1 = (const float*)d_in[1];
    const float* b1 = (const float*)d_in[2];
    const float* W2 = (const float*)d_in[3];
    const float* b2 = (const float*)d_in[4];
    const float* W3 = (const float*)d_in[5];
    const float* b3 = (const float*)d_in[6];
    float* out = (float*)d_out;

    int nrows = in_sizes[0] / 2;

    if (ws_size >= TAB_BYTES) {
        float4* tab = (float4*)d_ws;
        dim3 bgrid(NCELLS / BCELLS, NL);
        build_cells_kernel<<<bgrid, 320, 0, stream>>>(W1, b1, W2, b2, W3, b3, tab);
        int grid = (nrows + ROWS_PER_BLOCK - 1) / ROWS_PER_BLOCK;
        flow_lds_kernel<<<grid, TPB, 0, stream>>>(x, tab, out, nrows);
    } else {
        int grid = (nrows + 255) / 256;
        flow_fp32_kernel<<<grid, 256, 0, stream>>>(x, W1, b1, W2, b2, W3, b3, out, nrows);
    }
}

// Round 12
// 49.284 us; speedup vs baseline: 2.0433x; 2.0433x over previous
//
#include <hip/hip_runtime.h>
#include <hip/hip_bf16.h>
#include <string.h>

#define NL 32
#define HID 64

// Piecewise-linear f32 cell table over z1 in [-16, 16], 1024 cells (1/32).
// ReLU MLP on a scalar is exactly piecewise-linear; lerp + edge extrapolation
// validated rounds 1-10 (absmax 0.031 vs threshold 0.209, flat across widths
// 1/512..1/32). Cell: float4 (shift, scale=exp(ls), dshift, dscale) = 16 B,
// single ds_read_b128 gather, f32 lerp (fp16 lerp = 3x VALU, round-8 lesson).
#define NCELLS 1024
#define NNODES (NCELLS + 1)
#define SCALE  32.0f
#define OFFSET 512.0f
#define TAB_BYTES ((size_t)NL * NCELLS * sizeof(float4))   // 512 KB

#define TPB 512                      // 8 waves per block
#define RPT 4                        // rows per thread -> 1024 blocks = 4/CU
#define ROWS_PER_BLOCK (TPB * RPT)   // 2048
#define CHUNKS (NCELLS / TPB)        // 2 x 16B global_load_lds per thread/layer

#define GN 63                        // cells per build block (64 nodes, 1 overlap)

// ------------- build: wave-level j-split, weights stay wave-uniform --------
// Round-10 lesson: lane-level j-split (tid&3) broke wave-uniformity of
// w2row reads -> per-lane vector loads -> 70 us latency-bound. Here the
// j-split is PER WAVE: lane = node (64 nodes/block), wave w handles
// j in [4w, 4w+4). j0 via readfirstlane -> w2row pointer in SGPRs ->
// s_load broadcast, chain per thread ~320 FMA (vs 4288 in round 9).
__global__ __launch_bounds__(1024) void build_cells_kernel(
    const float* __restrict__ W1,
    const float* __restrict__ b1,
    const float* __restrict__ W2,
    const float* __restrict__ b2,
    const float* __restrict__ W3,
    const float* __restrict__ b3,
    float4* __restrict__ tab)
{
    const int tid  = threadIdx.x;
    const int lane = tid & 63;
    const int wave = tid >> 6;                 // 0..15
    const int l    = blockIdx.y;
    const int base = blockIdx.x * GN;          // cells [base, base+GN)

    __shared__ float2 part[64][17];            // padded: avoid 32-way write conflict
    __shared__ float2 nodes[64];

    const float* __restrict__ w1 = W1 + l * HID;
    const float* __restrict__ c1 = b1 + l * HID;
    const float* __restrict__ w2 = W2 + l * HID * HID;
    const float* __restrict__ c2 = b2 + l * HID;
    const float* __restrict__ w3 = W3 + l * 2 * HID;
    const float* __restrict__ c3 = b3 + l * 2;

    int node = base + lane;
    if (node > NCELLS) node = NCELLS;          // clamp (duplicate eval, harmless)
    float a = -16.0f + (float)node * (1.0f / 32.0f);   // exact in fp32

    float h1[HID];
    #pragma unroll
    for (int k = 0; k < HID; ++k) {
        float v = fmaxf(fmaf(a, w1[k], c1[k]), 0.0f);
        asm volatile("" : "+v"(v));            // pin in VGPR; block remat
        h1[k] = v;
    }

    // wave-uniform j subset: force the base row index into an SGPR
    const int j0 = __builtin_amdgcn_readfirstlane(wave * 4);

    float o0 = 0.0f;
    float o1 = 0.0f;
    #pragma unroll
    for (int jj = 0; jj < 4; ++jj) {
        const int j = j0 + jj;
        const float* __restrict__ w2row = w2 + j * HID;
        float acc0 = c2[j];
        float acc1 = 0.0f;
        #pragma unroll
        for (int k = 0; k < HID; k += 2) {
            acc0 = fmaf(h1[k],     w2row[k],     acc0);
            acc1 = fmaf(h1[k + 1], w2row[k + 1], acc1);
        }
        float h = fmaxf(acc0 + acc1, 0.0f);
        o0 = fmaf(h, w3[j], o0);
        o1 = fmaf(h, w3[HID + j], o1);
    }
    part[lane][wave] = make_float2(o0, o1);
    __syncthreads();

    if (tid < 64) {
        float s0 = c3[0];
        float s1 = c3[1];
        #pragma unroll
        for (int w = 0; w < 16; ++w) {
            float2 p = part[tid][w];
            s0 += p.x;
            s1 += p.y;
        }
        nodes[tid] = make_float2(s0, expf(s1));   // (shift, scale)
    }
    __syncthreads();

    if (tid < GN && base + tid < NCELLS) {
        float2 v0 = nodes[tid];
        float2 v1 = nodes[tid + 1];
        tab[(size_t)l * NCELLS + base + tid] =
            make_float4(v0.x, v0.y, v1.x - v0.x, v1.y - v0.y);
    }
}

// ---------------- helpers ---------------------------------------------------
__device__ __forceinline__ float2 nt_load_f2(const float* p) {
    unsigned long long raw =
        __builtin_nontemporal_load((const unsigned long long*)p);
    float2 v;
    memcpy(&v, &raw, 8);
    return v;
}
__device__ __forceinline__ void nt_store_f2(float* p, float2 v) {
    unsigned long long raw;
    memcpy(&raw, &v, 8);
    __builtin_nontemporal_store(raw, (unsigned long long*)p);
}

// async global->LDS DMA, 16 B per lane; LDS dest wave-uniform base,
// lane i lands at base + i*16 (linear lane order -> legal here).
__device__ __forceinline__ void gl2lds16(const float4* g, float4* l) {
    __builtin_amdgcn_global_load_lds(
        (const __attribute__((address_space(1))) void*)g,
        (__attribute__((address_space(3))) void*)l,
        16, 0, 0);
}

// ---------------- main pass: f32 LDS cell table, DMA staging, 4 blocks/CU --
// (unchanged from round 10: ~30 us, near the LDS gather-pipe limit)
__global__ __launch_bounds__(TPB, 8) void flow_lds_kernel(
    const float* __restrict__ x,
    const float4* __restrict__ tabg,
    float* __restrict__ out,
    int nrows)
{
    __shared__ float4 buf[2][NCELLS];   // 2 x 16 KiB

    const int tid = threadIdx.x;
    const int wbase = tid & ~63;        // wave-uniform lane-0 index
    const size_t rbase = (size_t)blockIdx.x * ROWS_PER_BLOCK;

    float a[RPT], b[RPT];
    #pragma unroll
    for (int i = 0; i < RPT; ++i) {
        size_t r = rbase + (size_t)i * TPB + tid;
        float2 z = (r < (size_t)nrows) ? nt_load_f2(x + 2 * r)
                                       : make_float2(0.f, 0.f);
        a[i] = z.x;
        b[i] = z.y;
    }

    // stage layer 0 into buf[0] (DMA); __syncthreads drains vmcnt
    #pragma unroll
    for (int c = 0; c < CHUNKS; ++c)
        gl2lds16(tabg + c * TPB + tid, &buf[0][c * TPB + wbase]);
    __syncthreads();

    int cur = 0;
    for (int l = 0; l < NL; ++l) {
        // issue next-layer DMA into the other half (in flight during gather)
        if (l + 1 < NL) {
            const float4* __restrict__ src = tabg + (size_t)(l + 1) * NCELLS;
            #pragma unroll
            for (int c = 0; c < CHUNKS; ++c)
                gl2lds16(src + c * TPB + tid, &buf[cur ^ 1][c * TPB + wbase]);
        }

        // gather-compute current layer from buf[cur] (f32 lerp, 3 fmaf)
        #pragma unroll
        for (int i = 0; i < RPT; ++i) {
            float t = fmaf(a[i], SCALE, OFFSET);
            int idx = (int)t;
            idx = idx < 0 ? 0 : (idx > NCELLS - 1 ? NCELLS - 1 : idx);
            float f = t - (float)idx;            // out-of-range -> extrapolate
            float4 nd = buf[cur][idx];
            float sh = fmaf(f, nd.z, nd.x);
            float sc = fmaf(f, nd.w, nd.y);
            float nb = fmaf(b[i], sc, sh);
            b[i] = a[i];
            a[i] = nb;
        }

        __syncthreads();   // waits vmcnt(0) + lgkmcnt(0), then barrier
        cur ^= 1;
    }

    #pragma unroll
    for (int i = 0; i < RPT; ++i) {
        size_t r = rbase + (size_t)i * TPB + tid;
        if (r < (size_t)nrows)
            nt_store_f2(out + 2 * r, make_float2(a[i], b[i]));
    }
}

// ---------------- fallback: direct fp32 (ws too small) ---------------------
__global__ __launch_bounds__(256, 2) void flow_fp32_kernel(
    const float* __restrict__ x,
    const float* __restrict__ W1,
    const float* __restrict__ b1,
    const float* __restrict__ W2,
    const float* __restrict__ b2,
    const float* __restrict__ W3,
    const float* __restrict__ b3,
    float* __restrict__ out,
    int nrows)
{
    int row = blockIdx.x * blockDim.x + threadIdx.x;
    if (row >= nrows) return;

    float2 z = reinterpret_cast<const float2*>(x)[row];
    float a = z.x;
    float b = z.y;

    for (int l = 0; l < NL; ++l) {
        const float* __restrict__ w1 = W1 + l * HID;
        const float* __restrict__ c1 = b1 + l * HID;
        const float* __restrict__ w2 = W2 + l * HID * HID;
        const float* __restrict__ c2 = b2 + l * HID;
        const float* __restrict__ w3 = W3 + l * 2 * HID;
        const float* __restrict__ c3 = b3 + l * 2;

        float h1[HID];
        #pragma unroll
        for (int k = 0; k < HID; ++k) {
            float v = fmaxf(fmaf(a, w1[k], c1[k]), 0.0f);
            asm volatile("" : "+v"(v));
            h1[k] = v;
        }

        float o0 = c3[0];
        float o1 = c3[1];

        #pragma unroll 2
        for (int j = 0; j < HID; ++j) {
            const float* __restrict__ w2row = w2 + j * HID;
            float acc0 = c2[j];
            float acc1 = 0.0f;
            #pragma unroll
            for (int k = 0; k < HID; k += 2) {
                acc0 = fmaf(h1[k],     w2row[k],     acc0);
                acc1 = fmaf(h1[k + 1], w2row[k + 1], acc1);
            }
            float h = fmaxf(acc0 + acc1, 0.0f);
            o0 = fmaf(h, w3[j], o0);
            o1 = fmaf(h, w3[HID + j], o1);
        }

        float nb = fmaf(b, __expf(o1), o0);
        b = a;
        a = nb;
    }

    reinterpret_cast<float2*>(out)[row] = make_float2(a, b);
}

extern "C" void kernel_launch(void* const* d_in, const int* in_sizes, int n_in,
                              void* d_out, int out_size, void* d_ws, size_t ws_size,
                              hipStream_t stream)
{
    const float* x  = (const float*)d_in[0];
    const float* W1 = (const float*)d_in[1];
    const float* b1 = (const float*)d_in[2];
    const float* W2 = (const float*)d_in[3];
    const float* b2 = (const float*)d_in[4];
    const float* W3 = (const float*)d_in[5];
    const float* b3 = (const float*)d_in[6];
    float* out = (float*)d_out;

    int nrows = in_sizes[0] / 2;

    if (ws_size >= TAB_BYTES) {
        float4* tab = (float4*)d_ws;
        dim3 bgrid((NCELLS + GN - 1) / GN, NL);
        build_cells_kernel<<<bgrid, 1024, 0, stream>>>(W1, b1, W2, b2, W3, b3, tab);
        int grid = (nrows + ROWS_PER_BLOCK - 1) / ROWS_PER_BLOCK;
        flow_lds_kernel<<<grid, TPB, 0, stream>>>(x, tab, out, nrows);
    } else {
        int grid = (nrows + 255) / 256;
        flow_fp32_kernel<<<grid, 256, 0, stream>>>(x, W1, b1, W2, b2, W3, b3, out, nrows);
    }
}

// Round 13
// 43.215 us; speedup vs baseline: 2.3303x; 1.1404x over previous
//
#include <hip/hip_runtime.h>
#include <hip/hip_bf16.h>
#include <string.h>

#define NL 32
#define HID 64

// Piecewise-linear f32 cell table over z1 in [-16, 16], 512 cells (1/16).
// ReLU MLP on a scalar is exactly piecewise-linear; lerp + edge extrapolation
// validated rounds 1-11 (f32-lerp absmax flat at 0.031 for widths 1/128..1/32
// -> kink error not binding). Cell: float4 (shift, scale=exp(ls), dshift,
// dscale) = 16 B, single ds_read_b128 gather, f32 lerp. Smaller table also
// increases same-address broadcasts (free) -> fewer bank conflicts.
#define NCELLS 512
#define NNODES (NCELLS + 1)
#define SCALE  16.0f
#define OFFSET 256.0f
#define TAB_BYTES ((size_t)NL * NCELLS * sizeof(float4))   // 256 KB

#define TPB 256                      // 4 waves per block
#define RPT 4                        // rows per thread -> 2048 blocks = 8/CU
#define ROWS_PER_BLOCK (TPB * RPT)   // 1024
#define CHUNKS (NCELLS / TPB)        // 2 x 16B global_load_lds per thread/layer

#define GN 63                        // cells per build block (64 nodes, 1 overlap)

// ------------- build: wave-level j-split, weights stay wave-uniform --------
// Lane = node (64 nodes/block), wave w handles j in [4w, 4w+4); j0 via
// readfirstlane -> w2row reads stay SGPR broadcast (round-10 lesson: lane-
// level split demotes them to per-lane vector loads, 70 us).
__global__ __launch_bounds__(1024) void build_cells_kernel(
    const float* __restrict__ W1,
    const float* __restrict__ b1,
    const float* __restrict__ W2,
    const float* __restrict__ b2,
    const float* __restrict__ W3,
    const float* __restrict__ b3,
    float4* __restrict__ tab)
{
    const int tid  = threadIdx.x;
    const int lane = tid & 63;
    const int wave = tid >> 6;                 // 0..15
    const int l    = blockIdx.y;
    const int base = blockIdx.x * GN;          // cells [base, base+GN)

    __shared__ float2 part[64][17];            // padded: avoid write conflicts
    __shared__ float2 nodes[64];

    const float* __restrict__ w1 = W1 + l * HID;
    const float* __restrict__ c1 = b1 + l * HID;
    const float* __restrict__ w2 = W2 + l * HID * HID;
    const float* __restrict__ c2 = b2 + l * HID;
    const float* __restrict__ w3 = W3 + l * 2 * HID;
    const float* __restrict__ c3 = b3 + l * 2;

    int node = base + lane;
    if (node > NCELLS) node = NCELLS;          // clamp (duplicate eval, harmless)
    float a = -16.0f + (float)node * (1.0f / 16.0f);   // exact in fp32

    float h1[HID];
    #pragma unroll
    for (int k = 0; k < HID; ++k) {
        float v = fmaxf(fmaf(a, w1[k], c1[k]), 0.0f);
        asm volatile("" : "+v"(v));            // pin in VGPR; block remat
        h1[k] = v;
    }

    // wave-uniform j subset: force the base row index into an SGPR
    const int j0 = __builtin_amdgcn_readfirstlane(wave * 4);

    float o0 = 0.0f;
    float o1 = 0.0f;
    #pragma unroll
    for (int jj = 0; jj < 4; ++jj) {
        const int j = j0 + jj;
        const float* __restrict__ w2row = w2 + j * HID;
        float acc0 = c2[j];
        float acc1 = 0.0f;
        #pragma unroll
        for (int k = 0; k < HID; k += 2) {
            acc0 = fmaf(h1[k],     w2row[k],     acc0);
            acc1 = fmaf(h1[k + 1], w2row[k + 1], acc1);
        }
        float h = fmaxf(acc0 + acc1, 0.0f);
        o0 = fmaf(h, w3[j], o0);
        o1 = fmaf(h, w3[HID + j], o1);
    }
    part[lane][wave] = make_float2(o0, o1);
    __syncthreads();

    if (tid < 64) {
        float s0 = c3[0];
        float s1 = c3[1];
        #pragma unroll
        for (int w = 0; w < 16; ++w) {
            float2 p = part[tid][w];
            s0 += p.x;
            s1 += p.y;
        }
        nodes[tid] = make_float2(s0, expf(s1));   // (shift, scale)
    }
    __syncthreads();

    if (tid < GN && base + tid < NCELLS) {
        float2 v0 = nodes[tid];
        float2 v1 = nodes[tid + 1];
        tab[(size_t)l * NCELLS + base + tid] =
            make_float4(v0.x, v0.y, v1.x - v0.x, v1.y - v0.y);
    }
}

// ---------------- helpers ---------------------------------------------------
__device__ __forceinline__ float2 nt_load_f2(const float* p) {
    unsigned long long raw =
        __builtin_nontemporal_load((const unsigned long long*)p);
    float2 v;
    memcpy(&v, &raw, 8);
    return v;
}
__device__ __forceinline__ void nt_store_f2(float* p, float2 v) {
    unsigned long long raw;
    memcpy(&raw, &v, 8);
    __builtin_nontemporal_store(raw, (unsigned long long*)p);
}

// async global->LDS DMA, 16 B per lane; LDS dest wave-uniform base,
// lane i lands at base + i*16 (linear lane order -> legal here).
__device__ __forceinline__ void gl2lds16(const float4* g, float4* l) {
    __builtin_amdgcn_global_load_lds(
        (const __attribute__((address_space(1))) void*)g,
        (__attribute__((address_space(3))) void*)l,
        16, 0, 0);
}

// ------- main pass: 512-cell f32 LDS table, DMA staging, 8 blocks/CU -------
// TPB=256 (4 waves), 16 KB LDS/block -> 8 independent blocks per CU: barrier
// drains of one block hide under the gather phases of the other seven.
__global__ __launch_bounds__(TPB, 8) void flow_lds_kernel(
    const float* __restrict__ x,
    const float4* __restrict__ tabg,
    float* __restrict__ out,
    int nrows)
{
    __shared__ float4 buf[2][NCELLS];   // 2 x 8 KiB

    const int tid = threadIdx.x;
    const int wbase = tid & ~63;        // wave-uniform lane-0 index
    const size_t rbase = (size_t)blockIdx.x * ROWS_PER_BLOCK;

    float a[RPT], b[RPT];
    #pragma unroll
    for (int i = 0; i < RPT; ++i) {
        size_t r = rbase + (size_t)i * TPB + tid;
        float2 z = (r < (size_t)nrows) ? nt_load_f2(x + 2 * r)
                                       : make_float2(0.f, 0.f);
        a[i] = z.x;
        b[i] = z.y;
    }

    // stage layer 0 into buf[0] (DMA); __syncthreads drains vmcnt
    #pragma unroll
    for (int c = 0; c < CHUNKS; ++c)
        gl2lds16(tabg + c * TPB + tid, &buf[0][c * TPB + wbase]);
    __syncthreads();

    int cur = 0;
    for (int l = 0; l < NL; ++l) {
        // issue next-layer DMA into the other half (in flight during gather)
        if (l + 1 < NL) {
            const float4* __restrict__ src = tabg + (size_t)(l + 1) * NCELLS;
            #pragma unroll
            for (int c = 0; c < CHUNKS; ++c)
                gl2lds16(src + c * TPB + tid, &buf[cur ^ 1][c * TPB + wbase]);
        }

        // gather-compute current layer from buf[cur] (f32 lerp, 3 fmaf)
        #pragma unroll
        for (int i = 0; i < RPT; ++i) {
            float t = fmaf(a[i], SCALE, OFFSET);
            int idx = (int)t;
            idx = idx < 0 ? 0 : (idx > NCELLS - 1 ? NCELLS - 1 : idx);
            float f = t - (float)idx;            // out-of-range -> extrapolate
            float4 nd = buf[cur][idx];
            float sh = fmaf(f, nd.z, nd.x);
            float sc = fmaf(f, nd.w, nd.y);
            float nb = fmaf(b[i], sc, sh);
            b[i] = a[i];
            a[i] = nb;
        }

        __syncthreads();   // waits vmcnt(0) + lgkmcnt(0), then barrier
        cur ^= 1;
    }

    #pragma unroll
    for (int i = 0; i < RPT; ++i) {
        size_t r = rbase + (size_t)i * TPB + tid;
        if (r < (size_t)nrows)
            nt_store_f2(out + 2 * r, make_float2(a[i], b[i]));
    }
}

// ---------------- fallback: direct fp32 (ws too small) ---------------------
__global__ __launch_bounds__(256, 2) void flow_fp32_kernel(
    const float* __restrict__ x,
    const float* __restrict__ W1,
    const float* __restrict__ b1,
    const float* __restrict__ W2,
    const float* __restrict__ b2,
    const float* __restrict__ W3,
    const float* __restrict__ b3,
    float* __restrict__ out,
    int nrows)
{
    int row = blockIdx.x * blockDim.x + threadIdx.x;
    if (row >= nrows) return;

    float2 z = reinterpret_cast<const float2*>(x)[row];
    float a = z.x;
    float b = z.y;

    for (int l = 0; l < NL; ++l) {
        const float* __restrict__ w1 = W1 + l * HID;
        const float* __restrict__ c1 = b1 + l * HID;
        const float* __restrict__ w2 = W2 + l * HID * HID;
        const float* __restrict__ c2 = b2 + l * HID;
        const float* __restrict__ w3 = W3 + l * 2 * HID;
        const float* __restrict__ c3 = b3 + l * 2;

        float h1[HID];
        #pragma unroll
        for (int k = 0; k < HID; ++k) {
            float v = fmaxf(fmaf(a, w1[k], c1[k]), 0.0f);
            asm volatile("" : "+v"(v));
            h1[k] = v;
        }

        float o0 = c3[0];
        float o1 = c3[1];

        #pragma unroll 2
        for (int j = 0; j < HID; ++j) {
            const float* __restrict__ w2row = w2 + j * HID;
            float acc0 = c2[j];
            float acc1 = 0.0f;
            #pragma unroll
            for (int k = 0; k < HID; k += 2) {
                acc0 = fmaf(h1[k],     w2row[k],     acc0);
                acc1 = fmaf(h1[k + 1], w2row[k + 1], acc1);
            }
            float h = fmaxf(acc0 + acc1, 0.0f);
            o0 = fmaf(h, w3[j], o0);
            o1 = fmaf(h, w3[HID + j], o1);
        }

        float nb = fmaf(b, __expf(o1), o0);
        b = a;
        a = nb;
    }

    reinterpret_cast<float2*>(out)[row] = make_float2(a, b);
}

extern "C" void kernel_launch(void* const* d_in, const int* in_sizes, int n_in,
                              void* d_out, int out_size, void* d_ws, size_t ws_size,
                              hipStream_t stream)
{
    const float* x  = (const float*)d_in[0];
    const float* W1 = (const float*)d_in[1];
    const float* b1 = (const float*)d_in[2];
    const float* W2 = (const float*)d_in[3];
    const float* b2 = (const float*)d_in[4];
    const float* W3 = (const float*)d_in[5];
    const float* b3 = (const float*)d_in[6];
    float* out = (float*)d_out;

    int nrows = in_sizes[0] / 2;

    if (ws_size >= TAB_BYTES) {
        float4* tab = (float4*)d_ws;
        dim3 bgrid((NCELLS + GN - 1) / GN, NL);
        build_cells_kernel<<<bgrid, 1024, 0, stream>>>(W1, b1, W2, b2, W3, b3, tab);
        int grid = (nrows + ROWS_PER_BLOCK - 1) / ROWS_PER_BLOCK;
        flow_lds_kernel<<<grid, TPB, 0, stream>>>(x, tab, out, nrows);
    } else {
        int grid = (nrows + 255) / 256;
        flow_fp32_kernel<<<grid, 256, 0, stream>>>(x, W1, b1, W2, b2, W3, b3, out, nrows);
    }
}